// Round 3
// 2138.757 us; speedup vs baseline: 1.2326x; 1.2326x over previous
//
#include <hip/hip_runtime.h>

// Problem constants (reference: B=32, S=8192, D=32, C=256)
#define S_LEN 8192
#define BATCH 32
#define DH    32
#define NC    256

typedef float f32x2 __attribute__((ext_vector_type(2)));

// sigmoid via native exp + rcp (1-2 ulp; threshold is ~2% relative -> huge margin)
__device__ __forceinline__ float sigf(float x) {
    return __builtin_amdgcn_rcpf(1.0f + __expf(-x));
}
__device__ __forceinline__ float rdlane(float v, int l) {
    return __int_as_float(__builtin_amdgcn_readlane(__float_as_int(v), l));
}
__device__ __forceinline__ float bperm(int byte_addr, float v) {
    return __int_as_float(__builtin_amdgcn_ds_bpermute(byte_addr, __float_as_int(v)));
}

// Half-wave exchange. For input v (lane j holds value of column j&31 of its half):
//   hi_b[lane] = v[(lane&31)+32]  (hi-half value broadcast to BOTH halves)
//   lo_b[lane] = v[lane&31]       (lo-half value broadcast to BOTH halves)
// MODE 0: permlane32_swap with r[0]=hi-bcast (vdst.lo<->vsrc.hi semantics)
// MODE 1: permlane32_swap with r[1]=hi-bcast (vdst.hi<->vsrc.lo semantics)
// MODE 2: ds_bpermute fallback (round-0 known-good path)
// MODE is probed at runtime (wave-uniform) so the kernel is correct under
// either documented direction of the swap instruction.
template <int MODE>
__device__ __forceinline__ void half_exchange(float v, float& hi_b, float& lo_b,
                                              bool lo, int swap_addr) {
    if constexpr (MODE == 2) {
        const float p = bperm(swap_addr, v);   // partner lane's value
        hi_b = lo ? p : v;
        lo_b = lo ? v : p;
    } else {
        auto r = __builtin_amdgcn_permlane32_swap(
            __float_as_uint(v), __float_as_uint(v), false, false);
        if constexpr (MODE == 0) { hi_b = __uint_as_float(r[0]); lo_b = __uint_as_float(r[1]); }
        else                     { hi_b = __uint_as_float(r[1]); lo_b = __uint_as_float(r[0]); }
    }
}

template <int M> struct IC { static constexpr int value = M; };

// Gate update given pre-activation z1 (i|f) and z2 (g|o, g pre-scaled by 2):
//   s1: lo lanes = sig(i), hi lanes = sig(f)
//   s2: lo lanes = sig(2g) pre-affine -> tanh(g), hi lanes = sig(o)
// After the exchange every lane holds all four gate values for column
// (lane&31); c/h are replicated in both halves.
#define DO_GATES(Z1, Z2) do {                                   \
    const float s1_ = sigf(Z1);                                 \
    const float s2_ = fmaf(aa, sigf(Z2), bb);                   \
    float f_, i_, o_, g_;                                       \
    half_exchange<MODE>(s1_, f_, i_, lo, swap_addr);  /* f_=sig(f), i_=sig(i) all lanes */ \
    half_exchange<MODE>(s2_, o_, g_, lo, swap_addr);  /* o_=sig(o), g_=tanh(g) all lanes */ \
    c = fmaf(f_, c, i_ * g_);                                   \
    const float tc_ = fmaf(2.f, sigf(2.f * c), -1.f);           \
    h = o_ * tc_;                                               \
    *hp = h; hp += DH;     /* lanes j and j^32 write same value to same addr */ \
} while (0)

// One wave per batch. Lane j owns gate columns k1=j (i for j<32, f for j>=32)
// and k2=j+64 (g for j<32, o for j>=32). h for column (j&31) is replicated
// in both half-waves so v_readlane(h, d) d=0..31 gives the full hidden state.
__global__ __launch_bounds__(64, 1) void lstm_scan_kernel(
    const float* __restrict__ x,      // (B,S)
    const float* __restrict__ bos,    // (D)
    const float* __restrict__ W_in,   // (1,D)
    const float* __restrict__ b_in,   // (D)
    const float* __restrict__ Wx,     // (D,4D)
    const float* __restrict__ Wh,     // (D,4D)
    const float* __restrict__ b_lstm, // (4D)
    float* __restrict__ hs)           // (B,S,D) workspace
{
    const int b    = blockIdx.x;
    const int lane = threadIdx.x;     // 0..63
    const int col  = lane & 31;
    const int k1   = lane;
    const int k2   = lane + 64;
    const bool lo  = lane < 32;
    const int swap_addr = (lane ^ 32) << 2;

    // tanh(g) = 2*sig(2g)-1: fold the *2 into the g-gate weights at load time.
    const float m2f = lo ? 2.f : 1.f;
    const float aa  = lo ? 2.f : 1.f;
    const float bb  = lo ? -1.f : 0.f;

    // Recurrent weight columns live in VGPRs as packed f32 pairs -> v_pk_fma_f32.
    f32x2 wh1p[16], wh2p[16];
#pragma unroll
    for (int dd = 0; dd < 16; ++dd) {
        wh1p[dd].x = Wh[(2*dd    ) * 4 * DH + k1];
        wh1p[dd].y = Wh[(2*dd + 1) * 4 * DH + k1];
        wh2p[dd].x = Wh[(2*dd    ) * 4 * DH + k2] * m2f;
        wh2p[dd].y = Wh[(2*dd + 1) * 4 * DH + k2] * m2f;
    }

    // Rank-1 input projection constants:
    //   zx[t,k] = x[t-1]*v_k + u_k   (t>=1),   zx[0,k] = z0_k
    float u1 = b_lstm[k1], u2 = b_lstm[k2];
    float z01 = u1, z02 = u2;         // bos @ Wx + b_lstm (bos used raw)
    float v1 = 0.f, v2 = 0.f;
#pragma unroll
    for (int d = 0; d < DH; ++d) {
        const float wx1 = Wx[d * 4 * DH + k1];
        const float wx2 = Wx[d * 4 * DH + k2];
        const float wi = W_in[d];
        v1 = fmaf(wi, wx1, v1);  v2 = fmaf(wi, wx2, v2);
        const float bi = b_in[d];
        u1 = fmaf(bi, wx1, u1);  u2 = fmaf(bi, wx2, u2);
        const float bd = bos[d];
        z01 = fmaf(bd, wx1, z01); z02 = fmaf(bd, wx2, z02);
    }
    v2 *= m2f; u2 *= m2f; z02 *= m2f;

    const float* xb = x + (size_t)b * S_LEN;
    float* hp = hs + (size_t)b * S_LEN * DH + col;

    float c = 0.f, h = 0.f;

    // ---- runtime direction probe (wave-uniform, once per kernel) ----
    const unsigned li = (unsigned)lane;
    auto pr = __builtin_amdgcn_permlane32_swap(li, li, false, false);
    const unsigned a0 = __builtin_amdgcn_readfirstlane(pr[0]);
    const unsigned b0 = __builtin_amdgcn_readfirstlane(pr[1]);

    auto run = [&](auto mode_tag) {
        constexpr int MODE = decltype(mode_tag)::value;

        // ---- step 0 peeled (z comes straight from the bos projection) ----
        DO_GATES(z01, z02);

        // Prefetch first x chunk: lane holds x[t-1] for t = chunk*64 + lane
        float xc;
        {
            const int xi = lane - 1;
            xc = (xi >= 0) ? xb[xi] : 0.f;
        }

        for (int chunk = 0; chunk < S_LEN / 64; ++chunk) {
            // Prefetch next chunk's x while this chunk computes (fully hidden).
            float xn = 0.f;
            if (chunk + 1 < S_LEN / 64) xn = xb[(chunk + 1) * 64 - 1 + lane];

            const int i0 = (chunk == 0) ? 1 : 0;   // t=0 already done
            for (int i = i0; i < 64; ++i) {
                const float xs = rdlane(xc, i);
                const float zx1 = fmaf(xs, v1, u1);
                const float zx2 = fmaf(xs, v2, u2);

                // 4 packed accumulator chains per gate pair -> issue-bound.
                f32x2 a1[4], a2[4];
#pragma unroll
                for (int dd = 0; dd < 4; ++dd) {
                    f32x2 hh;
                    hh.x = rdlane(h, 2 * dd);
                    hh.y = rdlane(h, 2 * dd + 1);
                    a1[dd] = hh * wh1p[dd];
                    a2[dd] = hh * wh2p[dd];
                }
#pragma unroll
                for (int dd = 4; dd < 16; ++dd) {
                    f32x2 hh;
                    hh.x = rdlane(h, 2 * dd);
                    hh.y = rdlane(h, 2 * dd + 1);
                    a1[dd & 3] += hh * wh1p[dd];
                    a2[dd & 3] += hh * wh2p[dd];
                }
                const f32x2 r1 = (a1[0] + a1[1]) + (a1[2] + a1[3]);
                const f32x2 r2 = (a2[0] + a2[1]) + (a2[2] + a2[3]);
                const float z1 = (zx1 + r1.x) + r1.y;
                const float z2 = (zx2 + r2.x) + r2.y;

                DO_GATES(z1, z2);
            }
            xc = xn;
        }
    };

    if (a0 == 32u && b0 == 0u)      run(IC<0>{});  // r0 = hi-bcast
    else if (a0 == 0u && b0 == 32u) run(IC<1>{});  // r1 = hi-bcast
    else                            run(IC<2>{});  // unknown semantics -> bpermute
}

// Projection: logits[b,t,c] = hs[b,t,:] @ W_out[:,c] + b_out[c]
// Block = 256 threads, one output column per thread, 128 t-rows per block.
// W_out column packed in VGPRs; h rows staged in LDS, read as ds_read_b128
// (broadcast, conflict-free); v_pk_fma_f32 inner product; coalesced stores.
__global__ __launch_bounds__(256, 4) void proj_kernel(
    const float* __restrict__ hs,     // (B,S,D)
    const float* __restrict__ W_out,  // (D,C)
    const float* __restrict__ b_out,  // (C)
    float* __restrict__ out)          // (B,S,C)
{
    __shared__ float hbuf[128 * DH];  // 16 KiB
    const int tid = threadIdx.x;
    const int b   = blockIdx.y;
    const int t0  = blockIdx.x * 128;

    // Stage 128 rows of h (coalesced float4 copy)
    const float4* src4 = (const float4*)(hs + ((size_t)b * S_LEN + t0) * DH);
    float4* dst4 = (float4*)hbuf;
#pragma unroll
    for (int k = 0; k < 4; ++k) dst4[tid + k * 256] = src4[tid + k * 256];
    __syncthreads();

    const int cc = tid;               // output column
    f32x2 w2[16];
#pragma unroll
    for (int d = 0; d < 16; ++d) {
        w2[d].x = W_out[(2*d    ) * NC + cc];
        w2[d].y = W_out[(2*d + 1) * NC + cc];
    }
    const float bo = b_out[cc];

    float* dst = out + ((size_t)b * S_LEN + t0) * NC + cc;
#pragma unroll 2
    for (int r = 0; r < 128; ++r) {
        const float4* row4 = (const float4*)(hbuf + r * DH);
        f32x2 acc_a; acc_a.x = 0.f; acc_a.y = 0.f;
        f32x2 acc_b; acc_b.x = 0.f; acc_b.y = 0.f;
#pragma unroll
        for (int q = 0; q < 8; ++q) {
            const float4 hv = row4[q];
            f32x2 h01; h01.x = hv.x; h01.y = hv.y;
            f32x2 h23; h23.x = hv.z; h23.y = hv.w;
            acc_a += h01 * w2[2*q];
            acc_b += h23 * w2[2*q + 1];
        }
        const f32x2 s = acc_a + acc_b;
        dst[(size_t)r * NC] = (bo + s.x) + s.y;  // 64 consecutive lanes -> coalesced
    }
}

extern "C" void kernel_launch(void* const* d_in, const int* in_sizes, int n_in,
                              void* d_out, int out_size, void* d_ws, size_t ws_size,
                              hipStream_t stream) {
    const float* x      = (const float*)d_in[0];
    const float* bos    = (const float*)d_in[1];
    const float* W_in   = (const float*)d_in[2];
    const float* b_in   = (const float*)d_in[3];
    const float* Wx     = (const float*)d_in[4];
    const float* Wh     = (const float*)d_in[5];
    const float* b_lstm = (const float*)d_in[6];
    const float* W_out  = (const float*)d_in[7];
    const float* b_out  = (const float*)d_in[8];

    float* out = (float*)d_out;
    float* hs  = (float*)d_ws;   // needs B*S*D*4 = 33.5 MB of workspace

    lstm_scan_kernel<<<dim3(BATCH), dim3(64), 0, stream>>>(
        x, bos, W_in, b_in, Wx, Wh, b_lstm, hs);
    proj_kernel<<<dim3(S_LEN / 128, BATCH), dim3(256), 0, stream>>>(
        hs, W_out, b_out, out);
}